// Round 8
// baseline (128.451 us; speedup 1.0000x reference)
//
#include <hip/hip_runtime.h>
#include <stdint.h>

#define N_ROWS 8192
#define FEAT   256
#define RB     256                    // rows per unit block
#define NB     (N_ROWS / RB)          // 32 row-blocks
#define NPAIR  (NB * (NB + 1) / 2)    // 528 (a<=b) pairs
#define NSLOT  (2 * NB)               // 64 partial slots per row

typedef __bf16 bf16x8 __attribute__((ext_vector_type(8)));
typedef float  f32x4  __attribute__((ext_vector_type(4)));

__device__ __forceinline__ unsigned short f2bf(float x) {
    union { float f; uint32_t u; } v; v.f = x;
    uint32_t u = v.u;
    return (unsigned short)((u + 0x7FFFu + ((u >> 16) & 1u)) >> 16);
}

// ---- Kernel 1: normalize rows -> bf16 copy (16B-chunk XOR-swizzled rows);
//      fused positive-pair dot. 4 waves/block = 4 consecutive rows.
__global__ void knorm(const float* __restrict__ feat,
                      unsigned short* __restrict__ fb,
                      float* __restrict__ pos) {
    __shared__ float ex[4][FEAT];
    int wave = threadIdx.x >> 6;
    int lane = threadIdx.x & 63;
    int row  = blockIdx.x * 4 + wave;
    float4 v = ((const float4*)(feat + row * FEAT))[lane];
    float ss = v.x*v.x + v.y*v.y + v.z*v.z + v.w*v.w;
    #pragma unroll
    for (int off = 1; off < 64; off <<= 1) ss += __shfl_xor(ss, off);
    float inv = 1.0f / fmaxf(sqrtf(ss), 1e-12f);
    float4 o; o.x = v.x*inv; o.y = v.y*inv; o.z = v.z*inv; o.w = v.w*inv;
    ushort4 b;
    b.x = f2bf(o.x); b.y = f2bf(o.y); b.z = f2bf(o.z); b.w = f2bf(o.w);
    int sidx = (((lane >> 1) ^ (row & 7)) << 1) | (lane & 1);
    ((ushort4*)(fb + row * FEAT))[sidx] = b;
    ((float4*)ex[wave])[lane] = o;
    __syncthreads();
    float4 p = ((float4*)ex[wave ^ 1])[lane];
    float d = o.x*p.x + o.y*p.y + o.z*p.z + o.w*p.w;
    #pragma unroll
    for (int off = 1; off < 64; off <<= 1) d += __shfl_xor(d, off);
    if (lane == 0) pos[row] = d;
}

// ---- Kernel 2: SYMMETRIC barrier-free f@f^T exp-sum ----------------------
// Composition of the two independently-validated levers:
//  - R5: barrier-free L2-direct B reads (fb is 4 MB, L2-resident; no LDS,
//    no barriers -> no co-residency capacity pin, blocks stream freely).
//  - R3: each (a<=b) 256-row-pair x 128-col-half computed ONCE; exp values
//    credited to both row sums (rows of a) and col sums (rows of b).
// R7 showed the wall is the SUM of VMEM+MFMA+VALU pipe times (in-phase
// waves serialize pipes); symmetry halves every term. R3's null was a
// capacity artifact (2 blocks/CU x 2.06 rounds), absent here.
// partial slots: row-sums of unit (a,b,h) -> slot 2b+h; col-sums -> slot 2a
// (h-units cover disjoint 128-row halves of b). Diagonal units mask j==i
// via the tile-diagonal check and skip col-sums; diag h==0 zero-fills the
// never-written slots {2j+1 : j<a}.
__global__ __launch_bounds__(256, 1)
void kmain(const unsigned short* __restrict__ fb, float* __restrict__ partial) {
    __shared__ float colred[4][128];             // 2 KB (epilogue only)
    const int t    = threadIdx.x;
    const int lane = t & 63;
    const int wave = t >> 6;          // 0..3
    const int quad = lane >> 4;       // 0..3
    const int l15  = lane & 15;

    // decode blockIdx.x -> (a, b, h): pair index row-major over a<=b
    const int pair = blockIdx.x >> 1;
    const int h    = blockIdx.x & 1;
    int a = 0, rem = pair;
    while (rem >= NB - a) { rem -= NB - a; ++a; }
    const int b = a + rem;
    const bool isdiag = (a == b);

    const int rw    = a * RB + wave * 64;        // this wave's 64 A-rows
    const int cbase = b * RB + h * 128;          // this block's 128 B-cols
    const float Kc = 20.60992915555662f;         // log2(e)/0.07

    // A fragments: 64 rows x K=256 resident in registers
    bf16x8 af[4][8];
    #pragma unroll
    for (int rf = 0; rf < 4; ++rf)
        #pragma unroll
        for (int ks = 0; ks < 8; ++ks) {
            int row = rw + rf * 16 + l15;
            int ch  = (ks * 4 + quad) ^ (row & 7);   // undo layout swizzle
            af[rf][ks] = *(const bf16x8*)(fb + row * FEAT + ch * 8);
        }

    float lsum[4][4] = {{0.f,0.f,0.f,0.f},{0.f,0.f,0.f,0.f},
                        {0.f,0.f,0.f,0.f},{0.f,0.f,0.f,0.f}};
    float cs[8] = {0.f,0.f,0.f,0.f,0.f,0.f,0.f,0.f};

    #pragma unroll 2
    for (int g = 0; g < 8; ++g) {                // 128 cols = 8 groups of 16
        const int cg = cbase + g * 16;
        const int C  = cg + l15;
        // lane's B-row (= similarity column) base; (cg+l15)&7 == l15&7
        const unsigned short* bp = fb + (size_t)(cg + l15) * FEAT;
        f32x4 ac0 = {0.f,0.f,0.f,0.f};
        f32x4 ac1 = {0.f,0.f,0.f,0.f};
        f32x4 ac2 = {0.f,0.f,0.f,0.f};
        f32x4 ac3 = {0.f,0.f,0.f,0.f};
        #pragma unroll
        for (int ks = 0; ks < 8; ++ks) {
            bf16x8 bv = *(const bf16x8*)(bp + (((ks * 4 + quad) ^ (l15 & 7)) * 8));
            ac0 = __builtin_amdgcn_mfma_f32_16x16x32_bf16(af[0][ks], bv, ac0, 0, 0, 0);
            ac1 = __builtin_amdgcn_mfma_f32_16x16x32_bf16(af[1][ks], bv, ac1, 0, 0, 0);
            ac2 = __builtin_amdgcn_mfma_f32_16x16x32_bf16(af[2][ks], bv, ac2, 0, 0, 0);
            ac3 = __builtin_amdgcn_mfma_f32_16x16x32_bf16(af[3][ks], bv, ac3, 0, 0, 0);
        }
        #pragma unroll
        for (int rf = 0; rf < 4; ++rf) {
            const int rb = rw + rf * 16;
            const bool dg = (cg == rb);   // only possible on diagonal units
            const f32x4 ac = (rf == 0) ? ac0 : (rf == 1) ? ac1
                           : (rf == 2) ? ac2 : ac3;
            #pragma unroll
            for (int r = 0; r < 4; ++r) {
                float e = __builtin_amdgcn_exp2f(fmaf(ac[r], Kc, -Kc));
                if (dg && (rb + quad * 4 + r == C)) e = 0.f;  // mask j == i
                lsum[rf][r] += e;
                cs[g] += e;
            }
        }
    }

    // ---- row sums -> partial[2b+h][rows of a] ----------------------------
    const int rslot = 2 * b + h;
    #pragma unroll
    for (int rf = 0; rf < 4; ++rf)
        #pragma unroll
        for (int r = 0; r < 4; ++r) {
            float v = lsum[rf][r];
            v += __shfl_xor(v, 1);
            v += __shfl_xor(v, 2);
            v += __shfl_xor(v, 4);
            v += __shfl_xor(v, 8);
            lsum[rf][r] = v;
        }
    if (l15 == 0) {
        #pragma unroll
        for (int rf = 0; rf < 4; ++rf)
            #pragma unroll
            for (int r = 0; r < 4; ++r) {
                int row = rw + rf * 16 + quad * 4 + r;
                partial[rslot * N_ROWS + row] = lsum[rf][r];
            }
    }

    // ---- col sums -> partial[2a][rows of b, half h] ----------------------
    #pragma unroll
    for (int g = 0; g < 8; ++g) {
        float v = cs[g];
        v += __shfl_xor(v, 16);      // sum across quads (same col, diff rows)
        v += __shfl_xor(v, 32);
        if (lane < 16) colred[wave][g * 16 + l15] = v;
    }
    __syncthreads();
    if (!isdiag && t < 128) {
        float s = colred[0][t] + colred[1][t] + colred[2][t] + colred[3][t];
        partial[(2 * a) * N_ROWS + b * RB + h * 128 + t] = s;
    }
    // diagonal h==0 block zero-fills the slots no unit writes for block a
    if (isdiag && h == 0) {
        for (int j = 0; j < a; ++j)
            partial[(2 * j + 1) * N_ROWS + a * RB + t] = 0.f;
    }
}

// ---- Kernel 3: per-row loss + block tree-reduce --------------------------
__global__ void kreduce(const float* __restrict__ partial,
                        const float* __restrict__ pos,
                        float* __restrict__ bsum) {
    __shared__ float red[4];
    int row  = blockIdx.x * 256 + threadIdx.x;
    int wave = threadIdx.x >> 6;
    int lane = threadIdx.x & 63;
    float L = 0.f;
    #pragma unroll
    for (int p = 0; p < NSLOT; ++p) L += partial[p * N_ROWS + row];
    const float invT = 14.285714285714286f;
    // loss_i = (1 - pos_i)/T + ln2 * log2(L)   (v_log_f32 is log2)
    float loss = invT * (1.0f - pos[row])
               + 0.6931471805599453f * __builtin_amdgcn_logf(L);
    #pragma unroll
    for (int off = 1; off < 64; off <<= 1) loss += __shfl_xor(loss, off);
    if (lane == 0) red[wave] = loss;
    __syncthreads();
    if (threadIdx.x == 0)
        bsum[blockIdx.x] = red[0] + red[1] + red[2] + red[3];
}

// ---- Kernel 4: final 32 -> 1 ---------------------------------------------
__global__ void kfinal(const float* __restrict__ bsum, float* __restrict__ out) {
    int lane = threadIdx.x;
    float v = (lane < 32) ? bsum[lane] : 0.f;
    #pragma unroll
    for (int off = 1; off < 32; off <<= 1) v += __shfl_xor(v, off);
    if (lane == 0) out[0] = v * (1.0f / 8192.0f);
}

extern "C" void kernel_launch(void* const* d_in, const int* in_sizes, int n_in,
                              void* d_out, int out_size, void* d_ws, size_t ws_size,
                              hipStream_t stream) {
    const float* feat = (const float*)d_in[0];
    float* out = (float*)d_out;
    char* ws = (char*)d_ws;
    unsigned short* fb      = (unsigned short*)ws;                    // 4 MB bf16 (swizzled rows)
    float*          partial = (float*)(ws + (4u << 20));              // 2 MB (64 slots x 8192)
    float*          pos     = (float*)(ws + (6u << 20));              // 32 KB
    float*          bsum    = (float*)(ws + (6u << 20) + (1u << 15));

    knorm<<<N_ROWS / 4, 256, 0, stream>>>(feat, fb, pos);
    kmain<<<NPAIR * 2, 256, 0, stream>>>(fb, partial);
    kreduce<<<N_ROWS / 256, 256, 0, stream>>>(partial, pos, bsum);
    kfinal<<<1, 64, 0, stream>>>(bsum, out);
}

// Round 9
// 99.759 us; speedup vs baseline: 1.2876x; 1.2876x over previous
//
#include <hip/hip_runtime.h>
#include <stdint.h>

#define N_ROWS 8192
#define FEAT   256
#define RB     128                    // rows per unit block
#define NB     (N_ROWS / RB)          // 64 row-blocks
#define NPAIR  (NB * (NB + 1) / 2)    // 2080 (a<=b) pairs
#define NSLOT  NB                     // 64 partial slots per row (perfectly packed)
#define CT     64                     // cols staged per chunk (32 KB)

typedef __bf16 bf16x8 __attribute__((ext_vector_type(8)));
typedef float  f32x4  __attribute__((ext_vector_type(4)));

__device__ __forceinline__ unsigned short f2bf(float x) {
    union { float f; uint32_t u; } v; v.f = x;
    uint32_t u = v.u;
    return (unsigned short)((u + 0x7FFFu + ((u >> 16) & 1u)) >> 16);
}

__device__ __forceinline__ void gld16(const unsigned short* g, unsigned short* l) {
    // direct global->LDS, 16 B per lane; LDS dest wave-linear (it is)
    __builtin_amdgcn_global_load_lds((__attribute__((address_space(1))) void*)g,
                                     (__attribute__((address_space(3))) void*)l,
                                     16, 0, 0);
}

// ---- Kernel 1: normalize rows -> bf16 copy (16B-chunk XOR-swizzled rows);
//      fused positive-pair dot. 4 waves/block = 4 consecutive rows.
__global__ void knorm(const float* __restrict__ feat,
                      unsigned short* __restrict__ fb,
                      float* __restrict__ pos) {
    __shared__ float ex[4][FEAT];
    int wave = threadIdx.x >> 6;
    int lane = threadIdx.x & 63;
    int row  = blockIdx.x * 4 + wave;
    float4 v = ((const float4*)(feat + row * FEAT))[lane];
    float ss = v.x*v.x + v.y*v.y + v.z*v.z + v.w*v.w;
    #pragma unroll
    for (int off = 1; off < 64; off <<= 1) ss += __shfl_xor(ss, off);
    float inv = 1.0f / fmaxf(sqrtf(ss), 1e-12f);
    float4 o; o.x = v.x*inv; o.y = v.y*inv; o.z = v.z*inv; o.w = v.w*inv;
    ushort4 b;
    b.x = f2bf(o.x); b.y = f2bf(o.y); b.z = f2bf(o.z); b.w = f2bf(o.w);
    int sidx = (((lane >> 1) ^ (row & 7)) << 1) | (lane & 1);
    ((ushort4*)(fb + row * FEAT))[sidx] = b;
    ((float4*)ex[wave])[lane] = o;
    __syncthreads();
    float4 p = ((float4*)ex[wave ^ 1])[lane];
    float d = o.x*p.x + o.y*p.y + o.z*p.z + o.w*p.w;
    #pragma unroll
    for (int off = 1; off < 64; off <<= 1) d += __shfl_xor(d, off);
    if (lane == 0) pos[row] = d;
}

// ---- Kernel 2: SYMMETRIC LDS-staged f@f^T exp-sum, 4-blocks/CU -----------
// Unit (a<=b): 128 A-rows x 128 B-cols, computed once; exp credited to both
// row sums (rows of a, slot b) and col sums (rows of b, slot a). Perfectly
// packed: every row-block gets all 64 slots written exactly once (diag unit
// writes row-side only). Sized for residency (the R3/R8 lesson): 4 waves x
// 32 rows (af[2][8]=64 regs, total ~110 <= 128 -> 4 waves/SIMD) + single
// 32KB staging buffer + 2KB colred -> min(LDS,VGPR) = 4 blocks/CU. The
// intra-block barrier stalls are covered by the 3 other independent-phase
// blocks on the CU (m114 mechanism), and LDS staging keeps the per-CU
// VMEM-instruction count (the measured ~18.7cy/load serial TA/L1 resource)
// at ~1/4 of the L2-direct variants.
__global__ __launch_bounds__(256, 4)
void kmain(const unsigned short* __restrict__ fb, float* __restrict__ partial) {
    __shared__ unsigned short buf[CT * FEAT];    // 32 KB (single buffer)
    __shared__ float colred[4][RB];              //  2 KB
    const int t    = threadIdx.x;
    const int lane = t & 63;
    const int wave = t >> 6;          // 0..3
    const int quad = lane >> 4;       // 0..3
    const int l15  = lane & 15;

    // decode blockIdx.x -> (a, b): pair index row-major over a<=b
    int a = 0, rem = blockIdx.x;
    while (rem >= NB - a) { rem -= NB - a; ++a; }
    const int b = a + rem;
    const bool isdiag = (a == b);

    const int rw    = a * RB + wave * 32;        // this wave's 32 A-rows
    const int cbase = b * RB;                    // this unit's 128 B-cols
    const float Kc = 20.60992915555662f;         // log2(e)/0.07

#define STAGE(CC0) do {                                                       \
    const unsigned short* sp_ = fb + (size_t)(cbase + (CC0)) * FEAT + t * 8;  \
    unsigned short* dp_ = buf + t * 8;                                        \
    _Pragma("unroll")                                                         \
    for (int i_ = 0; i_ < 8; ++i_)                                            \
        gld16(sp_ + i_ * 2048, dp_ + i_ * 2048);                              \
} while (0)

    STAGE(0);          // chunk 0 in flight while we load A fragments

    // A fragments: 32 rows x K=256 resident in registers (64 VGPRs)
    bf16x8 af[2][8];
    #pragma unroll
    for (int rf = 0; rf < 2; ++rf)
        #pragma unroll
        for (int ks = 0; ks < 8; ++ks) {
            int row = rw + rf * 16 + l15;
            int ch  = (ks * 4 + quad) ^ (row & 7);   // undo layout swizzle
            af[rf][ks] = *(const bf16x8*)(fb + row * FEAT + ch * 8);
        }

    float lsum[2][4] = {{0.f,0.f,0.f,0.f},{0.f,0.f,0.f,0.f}};
    float cs[8] = {0.f,0.f,0.f,0.f,0.f,0.f,0.f,0.f};

    // one 64-col chunk from LDS: 4 groups of 16 cols
#define COMPUTE(CC0, CS0) do {                                                \
    _Pragma("unroll")                                                         \
    for (int g = 0; g < 4; ++g) {                                             \
        const int cg = cbase + (CC0) + g * 16;                                \
        const int C  = cg + l15;                                              \
        f32x4 ac0 = {0.f,0.f,0.f,0.f};                                        \
        f32x4 ac1 = {0.f,0.f,0.f,0.f};                                        \
        _Pragma("unroll")                                                     \
        for (int ks = 0; ks < 8; ++ks) {                                      \
            bf16x8 bv = *(const bf16x8*)(buf + (g * 16 + l15) * FEAT          \
                                        + (((ks * 4 + quad) ^ (l15 & 7)) * 8)); \
            ac0 = __builtin_amdgcn_mfma_f32_16x16x32_bf16(af[0][ks], bv, ac0, 0, 0, 0); \
            ac1 = __builtin_amdgcn_mfma_f32_16x16x32_bf16(af[1][ks], bv, ac1, 0, 0, 0); \
        }                                                                     \
        _Pragma("unroll")                                                     \
        for (int rf = 0; rf < 2; ++rf) {                                      \
            const int rb_ = rw + rf * 16;                                     \
            const bool dg_ = (cg == rb_);   /* only on diagonal units */      \
            const f32x4 ac = (rf == 0) ? ac0 : ac1;                           \
            _Pragma("unroll")                                                 \
            for (int r = 0; r < 4; ++r) {                                     \
                float e = __builtin_amdgcn_exp2f(fmaf(ac[r], Kc, -Kc));       \
                if (dg_ && (rb_ + quad * 4 + r == C)) e = 0.f; /* j == i */   \
                lsum[rf][r] += e;                                             \
                cs[(CS0) + g] += e;                                           \
            }                                                                 \
        }                                                                     \
    }                                                                         \
} while (0)

    asm volatile("s_waitcnt vmcnt(0)" ::: "memory");
    __builtin_amdgcn_s_barrier();
    COMPUTE(0, 0);                   // chunk 0
    __builtin_amdgcn_s_barrier();    // all waves done reading buf
    STAGE(CT);                       // chunk 1
    asm volatile("s_waitcnt vmcnt(0)" ::: "memory");
    __builtin_amdgcn_s_barrier();
    COMPUTE(CT, 4);                  // chunk 1

    // ---- row sums -> partial[b][rows of a] -------------------------------
    #pragma unroll
    for (int rf = 0; rf < 2; ++rf)
        #pragma unroll
        for (int r = 0; r < 4; ++r) {
            float v = lsum[rf][r];
            v += __shfl_xor(v, 1);
            v += __shfl_xor(v, 2);
            v += __shfl_xor(v, 4);
            v += __shfl_xor(v, 8);
            lsum[rf][r] = v;
        }
    if (l15 == 0) {
        #pragma unroll
        for (int rf = 0; rf < 2; ++rf)
            #pragma unroll
            for (int r = 0; r < 4; ++r) {
                int row = rw + rf * 16 + quad * 4 + r;
                partial[b * N_ROWS + row] = lsum[rf][r];
            }
    }

    // ---- col sums -> partial[a][rows of b] (skip on diagonal) ------------
    #pragma unroll
    for (int g = 0; g < 8; ++g) {
        float v = cs[g];
        v += __shfl_xor(v, 16);      // sum across quads (rows, same col)
        v += __shfl_xor(v, 32);
        if (lane < 16) colred[wave][g * 16 + l15] = v;
    }
    __syncthreads();
    if (!isdiag && t < RB) {
        float s = colred[0][t] + colred[1][t] + colred[2][t] + colred[3][t];
        partial[a * N_ROWS + b * RB + t] = s;
    }
}

// ---- Kernel 3: per-row loss. 128 blocks x 256 thr; wave w sums slots
// w*16..w*16+15 for 64 rows (coalesced 256B loads), combine via LDS.
__global__ void kreduce(const float* __restrict__ partial,
                        const float* __restrict__ pos,
                        float* __restrict__ bsum) {
    __shared__ float red[4][64];
    int wave = threadIdx.x >> 6;
    int lane = threadIdx.x & 63;
    int row0 = blockIdx.x * 64;
    float L = 0.f;
    #pragma unroll
    for (int p = 0; p < 16; ++p)
        L += partial[(size_t)(wave * 16 + p) * N_ROWS + row0 + lane];
    red[wave][lane] = L;
    __syncthreads();
    if (wave == 0) {
        float Lt = red[0][lane] + red[1][lane] + red[2][lane] + red[3][lane];
        int row = row0 + lane;
        const float invT = 14.285714285714286f;
        // loss_i = (1 - pos_i)/T + ln2 * log2(L)   (v_log_f32 is log2)
        float loss = invT * (1.0f - pos[row])
                   + 0.6931471805599453f * __builtin_amdgcn_logf(Lt);
        #pragma unroll
        for (int off = 1; off < 64; off <<= 1) loss += __shfl_xor(loss, off);
        if (lane == 0) bsum[blockIdx.x] = loss;
    }
}

// ---- Kernel 4: final 128 -> 1 --------------------------------------------
__global__ void kfinal(const float* __restrict__ bsum, float* __restrict__ out) {
    int lane = threadIdx.x;
    float v = bsum[lane] + bsum[lane + 64];
    #pragma unroll
    for (int off = 1; off < 64; off <<= 1) v += __shfl_xor(v, off);
    if (lane == 0) out[0] = v * (1.0f / 8192.0f);
}

extern "C" void kernel_launch(void* const* d_in, const int* in_sizes, int n_in,
                              void* d_out, int out_size, void* d_ws, size_t ws_size,
                              hipStream_t stream) {
    const float* feat = (const float*)d_in[0];
    float* out = (float*)d_out;
    char* ws = (char*)d_ws;
    unsigned short* fb      = (unsigned short*)ws;                    // 4 MB bf16 (swizzled rows)
    float*          partial = (float*)(ws + (4u << 20));              // 2 MB (64 slots x 8192)
    float*          pos     = (float*)(ws + (6u << 20));              // 32 KB
    float*          bsum    = (float*)(ws + (6u << 20) + (1u << 15)); // 512 B

    knorm<<<N_ROWS / 4, 256, 0, stream>>>(feat, fb, pos);
    kmain<<<NPAIR, 256, 0, stream>>>(fb, partial);
    kreduce<<<N_ROWS / 64, 256, 0, stream>>>(partial, pos, bsum);
    kfinal<<<1, 64, 0, stream>>>(bsum, out);
}